// Round 1
// baseline (401.944 us; speedup 1.0000x reference)
//
#include <hip/hip_runtime.h>

// CapsuleLinear dynamic routing, fully fused, fp32.
// N=64 samples, I=256 in_caps, O=128 out_caps, K=16 in_len, L=32 out_len, 3 iters.
//
// Grid: 256 blocks = (o in 0..127) x (n-half in 0..1), 512 threads/block.
// Each block owns one output capsule o and 32 samples; logits [32][256] live in LDS.
// priors are recomputed on each pass (5x) by streaming the 512KB weight slice from
// global (LLC-resident) while x (prob-weighted or raw) is staged in LDS.

#define ICAPS 256
#define OCAPS 128
#define KLEN  16
#define LLEN  32
#define TN    32
#define LGS   257        // logits row stride (pad +1)
#define XROW  20         // xt per-n stride: 16 k + 4 pad (keeps 16B alignment)
#define XIST  644        // xt per-i stride: 32*20 + 4 (breaks 32-bank periodicity)
#define SVS   33         // s/v row stride

__global__ __launch_bounds__(512)
void caps_route(const float* __restrict__ xg_all,
                const float* __restrict__ wg_all,
                float* __restrict__ out) {
    __shared__ float lg[TN * LGS];       // logits, 32.9 KB
    __shared__ float xt[32 * XIST];      // x staging / reduce buffer, 82.4 KB
    __shared__ float sv[TN * SVS];       // s then v (squashed outputs), 4.2 KB
    __shared__ float stm[TN];            // softmax row max
    __shared__ float sti[TN];            // softmax 1/denominator

    const int t   = threadIdx.x;
    const int o   = blockIdx.x >> 1;
    const int n0  = (blockIdx.x & 1) * TN;
    const int isp = t >> 4;              // 0..31  i-split
    const int lb  = (t >> 2) & 3;        // 0..3   l-block (8 l each)
    const int nb  = t & 3;               // 0..3   n-block (n = nb + 4q)
    const int l0  = lb * 8;

    const float* xg = xg_all + (size_t)n0 * ICAPS * KLEN;
    const float* wg = wg_all + (size_t)o * ICAPS * KLEN * LLEN;

    // zero logits (incl. pad)
    for (int j = t; j < TN * LGS; j += 512) lg[j] = 0.0f;
    __syncthreads();

    for (int iter = 0; iter < 3; ++iter) {
        // ---------------- softmax stats over i, per n ----------------
        {
            const int n = t >> 4, sub = t & 15;
            const float* row = &lg[n * LGS];
            float m = -1e30f;
            for (int j = 0; j < 16; ++j) m = fmaxf(m, row[sub + 16 * j]);
            for (int d = 1; d < 16; d <<= 1) m = fmaxf(m, __shfl_xor(m, d, 16));
            float s = 0.0f;
            for (int j = 0; j < 16; ++j) s += __expf(row[sub + 16 * j] - m);
            for (int d = 1; d < 16; d <<= 1) s += __shfl_xor(s, d, 16);
            if (sub == 0) { stm[n] = m; sti[n] = 1.0f / s; }
        }
        __syncthreads();

        // ---------------- A-pass: s[n][l] = sum_i prob*prior ----------------
        float acc[8][8];
        #pragma unroll
        for (int q = 0; q < 8; ++q)
            #pragma unroll
            for (int r = 0; r < 8; ++r) acc[q][r] = 0.0f;

        for (int st = 0; st < 8; ++st) {
            const int i0 = st * 32;
            __syncthreads();
            // stage z = prob[n][i] * x[n][i][k] for 32 i
            #pragma unroll
            for (int j = 0; j < 8; ++j) {
                const int f   = t * 8 + j;       // 0..4095 float4s
                const int n   = f >> 7;
                const int rem = f & 127;
                const int il  = rem >> 2;
                const int k4  = (rem & 3) * 4;
                const float4 xv = *(const float4*)(xg + (size_t)(n * ICAPS + i0 + il) * KLEN + k4);
                const float  e  = __expf(lg[n * LGS + i0 + il] - stm[n]) * sti[n];
                float4 zv; zv.x = e * xv.x; zv.y = e * xv.y; zv.z = e * xv.z; zv.w = e * xv.w;
                *(float4*)(&xt[il * XIST + n * XROW + k4]) = zv;
            }
            __syncthreads();
            // accumulate: this thread's i = i0 + isp
            const float* wp = wg + (size_t)(i0 + isp) * (KLEN * LLEN) + l0;
            const float* xp = &xt[isp * XIST];
            #pragma unroll
            for (int k4 = 0; k4 < 4; ++k4) {
                float xq[8][4];
                #pragma unroll
                for (int q = 0; q < 8; ++q)
                    *(float4*)(&xq[q][0]) = *(const float4*)(xp + (nb + 4 * q) * XROW + k4 * 4);
                #pragma unroll
                for (int kk = 0; kk < 4; ++kk) {
                    const int k = k4 * 4 + kk;
                    const float4 wa = *(const float4*)(wp + k * LLEN);
                    const float4 wb = *(const float4*)(wp + k * LLEN + 4);
                    #pragma unroll
                    for (int q = 0; q < 8; ++q) {
                        const float xv = xq[q][kk];
                        acc[q][0] = fmaf(xv, wa.x, acc[q][0]);
                        acc[q][1] = fmaf(xv, wa.y, acc[q][1]);
                        acc[q][2] = fmaf(xv, wa.z, acc[q][2]);
                        acc[q][3] = fmaf(xv, wa.w, acc[q][3]);
                        acc[q][4] = fmaf(xv, wb.x, acc[q][4]);
                        acc[q][5] = fmaf(xv, wb.y, acc[q][5]);
                        acc[q][6] = fmaf(xv, wb.z, acc[q][6]);
                        acc[q][7] = fmaf(xv, wb.w, acc[q][7]);
                    }
                }
            }
        }

        // reduce acc over the 32 i-splits: 4 in-wave (lane strides 16,32), 8 waves via LDS
        #pragma unroll
        for (int q = 0; q < 8; ++q)
            #pragma unroll
            for (int r = 0; r < 8; ++r) {
                float v = acc[q][r];
                v += __shfl_xor(v, 16, 64);
                v += __shfl_xor(v, 32, 64);
                acc[q][r] = v;
            }
        __syncthreads();                      // xt reusable as reduce buffer
        {
            const int wv = t >> 6, lane = t & 63;
            if (lane < 16) {                  // lane = lb*4+nb (isp-in-wave==0)
                float* rb = &xt[wv * 1024 + lane * 64];
                #pragma unroll
                for (int q = 0; q < 8; ++q)
                    #pragma unroll
                    for (int r = 0; r < 8; ++r) rb[q * 8 + r] = acc[q][r];
            }
        }
        __syncthreads();
        for (int c = t; c < 1024; c += 512) {
            const int tl  = c >> 6;           // lb*4+nb
            const int lbb = tl >> 2, nbb = tl & 3;
            const int qr  = c & 63, q = qr >> 3, r = qr & 7;
            float ssum = 0.0f;
            #pragma unroll
            for (int w8 = 0; w8 < 8; ++w8) ssum += xt[w8 * 1024 + tl * 64 + qr];
            sv[(nbb + 4 * q) * SVS + lbb * 8 + r] = ssum;
        }
        __syncthreads();

        // ---------------- squash ----------------
        {
            const int n = t >> 4, sub = t & 15;
            float a = sv[n * SVS + sub];
            float b = sv[n * SVS + sub + 16];
            float sq = a * a + b * b;
            for (int d = 1; d < 16; d <<= 1) sq += __shfl_xor(sq, d, 16);
            const float sc = sqrtf(sq) / (1.0f + sq);
            sv[n * SVS + sub]      = a * sc;
            sv[n * SVS + sub + 16] = b * sc;
        }
        __syncthreads();

        // ---------------- B-pass: logits += sum_l prior*v ----------------
        if (iter < 2) {
            for (int st = 0; st < 8; ++st) {
                const int i0 = st * 32;
                __syncthreads();
                // stage raw x
                #pragma unroll
                for (int j = 0; j < 8; ++j) {
                    const int f   = t * 8 + j;
                    const int n   = f >> 7;
                    const int rem = f & 127;
                    const int il  = rem >> 2;
                    const int k4  = (rem & 3) * 4;
                    const float4 xv = *(const float4*)(xg + (size_t)(n * ICAPS + i0 + il) * KLEN + k4);
                    *(float4*)(&xt[il * XIST + n * XROW + k4]) = xv;
                }
                __syncthreads();
                const int i = i0 + isp;
                const float* wp = wg + (size_t)i * (KLEN * LLEN) + l0;
                const float* xp = &xt[isp * XIST];
                float P[8][8];
                #pragma unroll
                for (int q = 0; q < 8; ++q)
                    #pragma unroll
                    for (int r = 0; r < 8; ++r) P[q][r] = 0.0f;
                #pragma unroll
                for (int k4 = 0; k4 < 4; ++k4) {
                    float xq[8][4];
                    #pragma unroll
                    for (int q = 0; q < 8; ++q)
                        *(float4*)(&xq[q][0]) = *(const float4*)(xp + (nb + 4 * q) * XROW + k4 * 4);
                    #pragma unroll
                    for (int kk = 0; kk < 4; ++kk) {
                        const int k = k4 * 4 + kk;
                        const float4 wa = *(const float4*)(wp + k * LLEN);
                        const float4 wb = *(const float4*)(wp + k * LLEN + 4);
                        #pragma unroll
                        for (int q = 0; q < 8; ++q) {
                            const float xv = xq[q][kk];
                            P[q][0] = fmaf(xv, wa.x, P[q][0]);
                            P[q][1] = fmaf(xv, wa.y, P[q][1]);
                            P[q][2] = fmaf(xv, wa.z, P[q][2]);
                            P[q][3] = fmaf(xv, wa.w, P[q][3]);
                            P[q][4] = fmaf(xv, wb.x, P[q][4]);
                            P[q][5] = fmaf(xv, wb.y, P[q][5]);
                            P[q][6] = fmaf(xv, wb.z, P[q][6]);
                            P[q][7] = fmaf(xv, wb.w, P[q][7]);
                        }
                    }
                }
                // delta[n][i] = sum_l P[n][l]*v[n][l]; reduce over the 4 l-blocks
                #pragma unroll
                for (int q = 0; q < 8; ++q) {
                    const float* vp = &sv[(nb + 4 * q) * SVS + l0];
                    float d0 = P[q][0] * vp[0] + P[q][1] * vp[1] + P[q][2] * vp[2] + P[q][3] * vp[3]
                             + P[q][4] * vp[4] + P[q][5] * vp[5] + P[q][6] * vp[6] + P[q][7] * vp[7];
                    d0 += __shfl_xor(d0, 4, 64);
                    d0 += __shfl_xor(d0, 8, 64);
                    if (lb == 0) lg[(nb + 4 * q) * LGS + i] += d0;
                }
            }
            __syncthreads();
        }
    }

    // ---------------- output: out[n0+n][o][l] = v[n][l] ----------------
    for (int c = t; c < 1024; c += 512) {
        const int n = c >> 5, l = c & 31;
        out[((size_t)(n0 + n) * OCAPS + o) * LLEN + l] = sv[n * SVS + l];
    }
}

extern "C" void kernel_launch(void* const* d_in, const int* in_sizes, int n_in,
                              void* d_out, int out_size, void* d_ws, size_t ws_size,
                              hipStream_t stream) {
    const float* x = (const float*)d_in[0];   // [64,256,16]
    const float* w = (const float*)d_in[1];   // [128,256,16,32]
    float* out = (float*)d_out;               // [64,128,32]
    caps_route<<<dim3(OCAPS * 2), dim3(512), 0, stream>>>(x, w, out);
}